// Round 5
// baseline (155.646 us; speedup 1.0000x reference)
//
#include <hip/hip_runtime.h>
#include <hip/hip_cooperative_groups.h>

namespace cg = cooperative_groups;

#define EPSF 1e-8f
#define R2C  0.0025f   // 0.05^2
#define NJ   32        // j-chunks (grid.y)

// ---------------- ws float-index layout ----------------
// [0]                    : ticket (unsigned, ACCUMULATING across launches —
//                          "prev % nbi == nbi-1" fires exactly once per launch
//                          for any start value, so no reset/memset needed)
// [64 + blk*8 + 0..6]    : prep rows {hx,hy,hz,nh,pv,gv,nb} (plain stores,
//                          read after grid.sync)
// [1024 + blk*16 + 0..11]: final rows {cov6, sd, sd2, maxd, sv, nv, pad}
//                          (atomic publish + atomic reads, R4-proven)
// [4096 + ...]           : pair partials cnt[NJ][n], sx[NJ][n], sx2[NJ][n]
// total ~3.2 MB << ws_size. Every word read is written earlier in the SAME launch.

__device__ inline int read_mask(const void* p, int i, int isInt) {
    if (isInt) return ((const int*)p)[i] != 0;
    return ((const unsigned char*)p)[i] != 0;
}
__device__ inline float wave_sum(float v) {
    #pragma unroll
    for (int o = 32; o > 0; o >>= 1) v += __shfl_down(v, o, 64);
    return v;
}
__device__ inline float wave_max(float v) {
    #pragma unroll
    for (int o = 32; o > 0; o >>= 1) v = fmaxf(v, __shfl_down(v, o, 64));
    return v;
}

__global__ __launch_bounds__(256, 4)
void k_fused(const float* __restrict__ pts, const float* __restrict__ segp,
             const void* bm, const void* hm, const void* pm, const void* gm,
             float* __restrict__ ws, float* __restrict__ out, int n, int nbi) {
    __shared__ float4 t4[256];
    __shared__ float2 tv[256];
    __shared__ int bad[4];
    __shared__ float pacc[8];    // prep sums
    __shared__ float ctr[8];     // reduced global counts/centroid
    __shared__ float bacc[12];   // final-row accumulators
    __shared__ int bmax, lastf;

    int tid = threadIdx.x, lane = tid & 63;
    int bx = blockIdx.x, c = blockIdx.y;

    if (tid < 4) bad[tid] = 0;
    if (tid < 8) pacc[tid] = 0.f;
    if (tid < 12) bacc[tid] = 0.f;
    if (tid == 0) { bmax = 0; lastf = 0; }
    __syncthreads();
    {   // mask layout detect: byte layout shows nonzero upper bytes in the
        // first 256 words unless the first 1024 bools are all false (p~2^-768)
        const void* ms[4] = {bm, hm, pm, gm};
        #pragma unroll
        for (int m = 0; m < 4; ++m) {
            unsigned w = ((const unsigned*)ms[m])[tid & 255];
            if (w & 0xFFFFFF00u) atomicOr(&bad[m], 1);
        }
    }
    __syncthreads();

    // ---- i-side data (registers, reused in phase B) ----
    int i = bx*256 + tid;
    int ic = min(i, n-1);
    bool act = i < n;
    float x = pts[3*ic], y = pts[3*ic+1], z = pts[3*ic+2];
    int b = read_mask(bm, ic, !bad[0]) && act;
    float sq = x*x + y*y + z*z;
    float sqi = b ? sq : sq + 1000.f;   // sentinel: non-boundary i never matches

    // ---- c==0 blocks: per-point sums -> prep row ----
    if (c == 0) {
        int h = read_mask(hm, ic, !bad[1]) && act;
        int p = read_mask(pm, ic, !bad[2]) && act;
        int g = read_mask(gm, ic, !bad[3]) && act;
        float hf = h ? 1.f : 0.f;
        float vals[7] = { hf*x, hf*y, hf*z, hf, (float)p, (float)g, (float)b };
        #pragma unroll
        for (int k = 0; k < 7; ++k) {
            float s = wave_sum(vals[k]);
            if (lane == 0) atomicAdd(&pacc[k], s);   // LDS atomic: on-CU, cheap
        }
        __syncthreads();
        if (tid < 7) ws[64 + bx*8 + tid] = pacc[tid];
    }

    // ---- pair tile sweep: tiles t = c, c+NJ, ... ----
    float* __restrict__ outb = ws + 4096;
    float ci = 0.f, s1 = 0.f, s2 = 0.f;
    for (int t = c; t < nbi; t += NJ) {
        int j = t*256 + tid;
        int jc = min(j, n-1);
        bool jact = j < n;
        float xj = pts[3*jc], yj = pts[3*jc+1], zj = pts[3*jc+2];
        int bj = read_mask(bm, jc, !bad[0]) && jact;
        float v = segp[3*jc+2];
        float sqj = xj*xj + yj*yj + zj*zj;
        __syncthreads();
        t4[tid] = make_float4(-2.f*xj, -2.f*yj, -2.f*zj, bj ? sqj : sqj + 1000.f);
        tv[tid] = make_float2(v, v*v);
        __syncthreads();
        #pragma unroll 8
        for (int k = 0; k < 256; ++k) {
            float4 pj = t4[k];
            float2 vv = tv[k];
            float acc = fmaf(pj.x, x, pj.w);
            acc = fmaf(pj.y, y, acc);
            acc = fmaf(pj.z, z, acc);
            float d2 = acc + sqi;
            float m = (d2 < R2C) ? 1.f : 0.f;
            ci += m;
            s1 = fmaf(m, vv.x, s1);
            s2 = fmaf(m, vv.y, s2);
        }
    }
    if (act) {
        outb[(size_t)c*n + i]          = ci;
        outb[(size_t)(NJ + c)*n + i]   = s1;
        outb[(size_t)(2*NJ + c)*n + i] = s2;
    }

    cg::this_grid().sync();   // cross-XCD visibility of rows + partials
    if (c != 0) return;

    // ================= phase B: blocks (bx, 0) only =================
    // global counts/centroid from prep rows (each block redundantly)
    if (tid < 64) {
        float s[7] = {0.f,0.f,0.f,0.f,0.f,0.f,0.f};
        for (int r = tid; r < nbi; r += 64)
            #pragma unroll
            for (int k = 0; k < 7; ++k) s[k] += ws[64 + r*8 + k];
        #pragma unroll
        for (int k = 0; k < 7; ++k) {
            #pragma unroll
            for (int o = 32; o > 0; o >>= 1) s[k] += __shfl_down(s[k], o, 64);
        }
        if (tid == 0) {
            #pragma unroll
            for (int k = 0; k < 7; ++k) ctr[k] = s[k];
        }
    }
    __syncthreads();

    float nh = ctr[3];
    float inv = (nh > 0.f) ? 1.f/nh : 0.f;
    float cx = ctr[0]*inv, cy = ctr[1]*inv, cz = ctr[2]*inv;
    int h = read_mask(hm, ic, !bad[1]) && act;
    float m = h ? 1.f : 0.f;
    float dx = x-cx, dy = y-cy, dz = z-cz;
    float d = sqrtf(dx*dx + dy*dy + dz*dz);
    {
        float vals[8] = { m*dx*dx, m*dx*dy, m*dx*dz, m*dy*dy, m*dy*dz, m*dz*dz,
                          m*d, m*d*d };
        #pragma unroll
        for (int k = 0; k < 8; ++k) {
            float s = wave_sum(vals[k]);
            if (lane == 0) atomicAdd(&bacc[k], s);
        }
        float dm = wave_max(m > 0.f ? d : 0.f);
        if (lane == 0) atomicMax(&bmax, __float_as_int(dm));
    }
    // reduce this i's pair partials (written by blocks (bx, 0..NJ-1))
    {
        float sv = 0.f, nv = 0.f;
        if (act) {
            float c0 = 0.f, a1 = 0.f, a2 = 0.f;
            #pragma unroll
            for (int k = 0; k < NJ; ++k) {
                c0 += outb[(size_t)k*n + i];
                a1 += outb[(size_t)(NJ + k)*n + i];
                a2 += outb[(size_t)(2*NJ + k)*n + i];
            }
            float safe_n = fmaxf(c0, 2.f);
            float var = (a2 - a1*a1/safe_n) / (safe_n - 1.f);
            if (b && c0 > 1.f) { sv = var; nv = 1.f; }
        }
        sv = wave_sum(sv); nv = wave_sum(nv);
        if (lane == 0) { atomicAdd(&bacc[9], sv); atomicAdd(&bacc[10], nv); }
    }
    __syncthreads();

    // publish per-block row (device-scope), then accumulating ticket
    float* row = ws + 1024 + bx*16;
    if (tid < 12) {
        float val = (tid == 8) ? __int_as_float(bmax) : bacc[tid];
        atomicExch((int*)&row[tid], __float_as_int(val));
    }
    if (tid == 0) {
        __threadfence();
        unsigned prev = atomicAdd((unsigned*)ws, 1u);
        if (prev % (unsigned)nbi == (unsigned)nbi - 1u) lastf = 1;
    }
    __syncthreads();
    if (!lastf) return;

    // last block: gather rows with atomic loads (distinct lines, parallel)
    if (tid < 12) bacc[tid] = 0.f;
    if (tid == 0) bmax = 0;
    __syncthreads();
    for (int t = tid; t < nbi*12; t += 256) {
        int r = t / 12, col = t % 12;
        int bits = atomicOr((int*)&ws[1024 + r*16 + col], 0);
        if (col == 8) atomicMax(&bmax, bits);
        else          atomicAdd(&bacc[col], __int_as_float(bits));
    }
    __syncthreads();
    if (tid != 0) return;

    float cxx=bacc[0], cxy=bacc[1], cxz=bacc[2];
    float cyy=bacc[3], cyz=bacc[4], czz=bacc[5];
    float sd=bacc[6], sd2=bacc[7], svv=bacc[9], niv=bacc[10];
    float maxd = __int_as_float(bmax);
    float pv = ctr[4], gv = ctr[5], nbm = ctr[6];

    // ellipsoid shape loss (closed-form symmetric 3x3 eigvals, double)
    float el = 0.0f;
    if (nh >= 10.0f) {
        double nn  = (double)nh;
        double axx = cxx/nn, axy = cxy/nn, axz = cxz/nn;
        double ayy = cyy/nn, ayz = cyz/nn, azz = czz/nn;
        double p1 = axy*axy + axz*axz + ayz*ayz;
        double q  = (axx + ayy + azz) / 3.0;
        double p2 = (axx-q)*(axx-q) + (ayy-q)*(ayy-q) + (azz-q)*(azz-q) + 2.0*p1;
        double e0, e2;
        if (p2 < 1e-300) { e0 = e2 = q; }
        else {
            double p = sqrt(p2 / 6.0);
            double bxx = (axx-q)/p, byy = (ayy-q)/p, bzz = (azz-q)/p;
            double bxy = axy/p, bxz = axz/p, byz = ayz/p;
            double detB = bxx*(byy*bzz - byz*byz) - bxy*(bxy*bzz - byz*bxz)
                        + bxz*(bxy*byz - byy*bxz);
            double r2 = fmin(1.0, fmax(-1.0, detB * 0.5));
            double phi = acos(r2) / 3.0;
            e2 = q + 2.0*p*cos(phi);                       // largest
            e0 = q + 2.0*p*cos(phi + 2.0943951023931953);  // smallest
        }
        double e1 = 3.0*q - e2 - e0;
        double ra = e1/(e2 + (double)EPSF) - 1.0;
        double rc = e0/(e2 + (double)EPSF) - 1.0;
        el = (float)(ra*ra + rc*rc);
    }
    // size consistency
    float diff = pv - gv;
    float vol = diff * diff;
    float rel = fabsf(diff) / (gv > 0.0f ? gv : 1.0f);
    float sc = (gv > 0.0f) ? vol + 0.5f*rel : vol;
    // surface smoothness
    float mean_var = svv / fmaxf(niv, 1.0f);
    float ss = ((nbm >= 5.0f) && (niv > 0.0f)) ? mean_var : 0.0f;
    // connectivity
    float conn = 0.0f;
    if (nh >= 5.0f) {
        float var = (sd2 - sd*sd/nh) / (nh - 1.0f);
        conn = var / (maxd + EPSF);
    }
    out[0] = el + sc + ss + conn;
}

extern "C" void kernel_launch(void* const* d_in, const int* in_sizes, int n_in,
                              void* d_out, int out_size, void* d_ws, size_t ws_size,
                              hipStream_t stream) {
    const float* points = (const float*)d_in[0];
    const float* segp   = (const float*)d_in[1];
    const void*  bmask  = d_in[2];
    const void*  hmask  = d_in[3];
    const void*  pmask  = d_in[4];
    const void*  gmask  = d_in[5];
    float* ws  = (float*)d_ws;
    float* out = (float*)d_out;
    int n = in_sizes[2];            // 8192
    int nbi = (n + 255) / 256;      // 32

    void* args[] = { (void*)&points, (void*)&segp, (void*)&bmask, (void*)&hmask,
                     (void*)&pmask, (void*)&gmask, (void*)&ws, (void*)&out,
                     (void*)&n, (void*)&nbi };
    hipLaunchCooperativeKernel(reinterpret_cast<void*>(&k_fused),
                               dim3(nbi, NJ), dim3(256), args, 0, stream);
}

// Round 6
// 31.378 us; speedup vs baseline: 4.9603x; 4.9603x over previous
//
#include <hip/hip_runtime.h>

#define EPSF 1e-8f
#define R2C  0.0025f   // 0.05^2
#define NJ   32        // j-chunks (grid.y of K1)

// ---------------- ws float-index layout ----------------
// [0]                    : ticket (unsigned, ACCUMULATING across launches —
//                          "prev % nbi == nbi-1" fires exactly once per launch
//                          for any start value, so no reset/memset needed)
// [64 + blk*8 + 0..6]    : K1 prep rows {hx,hy,hz,nh,pv,gv,nb} (plain stores;
//                          visible to K2 via kernel-boundary flush)
// [1024 + blk*16 + 0..11]: K2 per-block rows {cov6, sd, sd2, maxd, sv, nv, pad}
//                          (atomic publish + atomic reads, R4-proven)
// [4096 + ...]           : pair partials cnt[NJ][n], sx[NJ][n], sx2[NJ][n]
// total ~3.2 MB << ws_size. Every word K2 reads is written by K1/K2 this launch.

__device__ inline int read_mask(const void* p, int i, int isInt) {
    if (isInt) return ((const int*)p)[i] != 0;
    return ((const unsigned char*)p)[i] != 0;
}
__device__ inline float wave_sum(float v) {
    #pragma unroll
    for (int o = 32; o > 0; o >>= 1) v += __shfl_down(v, o, 64);
    return v;
}
__device__ inline float wave_max(float v) {
    #pragma unroll
    for (int o = 32; o > 0; o >>= 1) v = fmaxf(v, __shfl_down(v, o, 64));
    return v;
}

// K1: pair tile sweep from raw inputs; c==0 plane also emits prep rows.
__global__ __launch_bounds__(256, 4)
void k_pairs(const float* __restrict__ pts, const float* __restrict__ segp,
             const void* bm, const void* hm, const void* pm, const void* gm,
             float* __restrict__ ws, int n, int nbi) {
    __shared__ float4 t4[256];
    __shared__ float2 tv[256];
    __shared__ int bad[4];
    __shared__ float pacc[8];
    int tid = threadIdx.x, lane = tid & 63;
    int bx = blockIdx.x, c = blockIdx.y;

    if (tid < 4) bad[tid] = 0;
    if (tid < 8) pacc[tid] = 0.f;
    __syncthreads();
    {   // mask layout detect: byte layout shows nonzero upper bytes in the
        // first 256 words unless the first 1024 bools are all false (p~2^-768)
        const void* ms[4] = {bm, hm, pm, gm};
        #pragma unroll
        for (int m = 0; m < 4; ++m) {
            unsigned w = ((const unsigned*)ms[m])[tid & 255];
            if (w & 0xFFFFFF00u) atomicOr(&bad[m], 1);
        }
    }
    __syncthreads();

    int i = bx*256 + tid;
    int ic = min(i, n-1);
    bool act = i < n;
    float x = pts[3*ic], y = pts[3*ic+1], z = pts[3*ic+2];
    int b = read_mask(bm, ic, !bad[0]) && act;
    float sq = x*x + y*y + z*z;
    float sqi = b ? sq : sq + 1000.f;   // sentinel: non-boundary i never matches

    if (c == 0) {   // prep sums -> per-block row
        int h = read_mask(hm, ic, !bad[1]) && act;
        int p = read_mask(pm, ic, !bad[2]) && act;
        int g = read_mask(gm, ic, !bad[3]) && act;
        float hf = h ? 1.f : 0.f;
        float vals[7] = { hf*x, hf*y, hf*z, hf, (float)p, (float)g, (float)b };
        #pragma unroll
        for (int k = 0; k < 7; ++k) {
            float s = wave_sum(vals[k]);
            if (lane == 0) atomicAdd(&pacc[k], s);   // LDS atomic: on-CU, cheap
        }
        __syncthreads();
        if (tid < 7) ws[64 + bx*8 + tid] = pacc[tid];
    }

    float* __restrict__ outb = ws + 4096;
    float ci = 0.f, s1 = 0.f, s2 = 0.f;
    for (int t = c; t < nbi; t += NJ) {   // nbi==NJ => exactly one tile/block
        int j = t*256 + tid;
        int jc = min(j, n-1);
        bool jact = j < n;
        float xj = pts[3*jc], yj = pts[3*jc+1], zj = pts[3*jc+2];
        int bj = read_mask(bm, jc, !bad[0]) && jact;
        float v = segp[3*jc+2];
        float sqj = xj*xj + yj*yj + zj*zj;
        __syncthreads();
        t4[tid] = make_float4(-2.f*xj, -2.f*yj, -2.f*zj, bj ? sqj : sqj + 1000.f);
        tv[tid] = make_float2(v, v*v);
        __syncthreads();
        #pragma unroll 8
        for (int k = 0; k < 256; ++k) {
            float4 pj = t4[k];
            float2 vv = tv[k];
            float acc = fmaf(pj.x, x, pj.w);
            acc = fmaf(pj.y, y, acc);
            acc = fmaf(pj.z, z, acc);
            float d2 = acc + sqi;
            float m = (d2 < R2C) ? 1.f : 0.f;
            ci += m;
            s1 = fmaf(m, vv.x, s1);
            s2 = fmaf(m, vv.y, s2);
        }
    }
    if (act) {
        outb[(size_t)c*n + i]          = ci;
        outb[(size_t)(NJ + c)*n + i]   = s1;
        outb[(size_t)(2*NJ + c)*n + i] = s2;
    }
}

// K2: center-dependent reductions + partial reduce + last-block assembly.
__global__ void k_final(const float* __restrict__ pts, const void* bm, const void* hm,
                        float* __restrict__ ws, float* __restrict__ out, int n, int nbi) {
    __shared__ int badb, badh, lastf, bmax;
    __shared__ float ctr[8];
    __shared__ float bacc[12];
    int tid = threadIdx.x, lane = tid & 63;
    if (tid == 0) { badb = 0; badh = 0; lastf = 0; bmax = 0; }
    if (tid < 12) bacc[tid] = 0.f;
    __syncthreads();
    unsigned wb = ((const unsigned*)bm)[tid & 255];
    unsigned wh = ((const unsigned*)hm)[tid & 255];
    if (wb & 0xFFFFFF00u) atomicOr(&badb, 1);
    if (wh & 0xFFFFFF00u) atomicOr(&badh, 1);

    // sum prep rows (nbi <= 64) -> global counts & head centroid
    if (tid < 64) {
        float s[7] = {0.f,0.f,0.f,0.f,0.f,0.f,0.f};
        for (int r = tid; r < nbi; r += 64)
            #pragma unroll
            for (int k = 0; k < 7; ++k) s[k] += ws[64 + r*8 + k];
        #pragma unroll
        for (int k = 0; k < 7; ++k) {
            #pragma unroll
            for (int o = 32; o > 0; o >>= 1) s[k] += __shfl_down(s[k], o, 64);
        }
        if (tid == 0) {
            #pragma unroll
            for (int k = 0; k < 7; ++k) ctr[k] = s[k];
        }
    }
    __syncthreads();

    float nh = ctr[3];
    float inv = (nh > 0.f) ? 1.f/nh : 0.f;
    float cx = ctr[0]*inv, cy = ctr[1]*inv, cz = ctr[2]*inv;
    int i = blockIdx.x*256 + tid;
    int ic = min(i, n-1);
    float act = (i < n) ? 1.f : 0.f;
    float x = pts[3*ic], y = pts[3*ic+1], z = pts[3*ic+2];
    int h = read_mask(hm, ic, !badh);
    float m = (h ? 1.f : 0.f) * act;
    float dx = x-cx, dy = y-cy, dz = z-cz;
    float d = sqrtf(dx*dx + dy*dy + dz*dz);
    float vals[8] = { m*dx*dx, m*dx*dy, m*dx*dz, m*dy*dy, m*dy*dz, m*dz*dz,
                      m*d, m*d*d };
    #pragma unroll
    for (int k = 0; k < 8; ++k) {
        float s = wave_sum(vals[k]);
        if (lane == 0) atomicAdd(&bacc[k], s);
    }
    float dm = wave_max(m > 0.f ? d : 0.f);
    if (lane == 0) atomicMax(&bmax, __float_as_int(dm));

    // reduce this i's pair partials
    const float* __restrict__ outb = ws + 4096;
    float sv = 0.f, nv = 0.f;
    if (i < n) {
        float c0 = 0.f, a1 = 0.f, a2 = 0.f;
        #pragma unroll
        for (int k = 0; k < NJ; ++k) {
            c0 += outb[(size_t)k*n + i];
            a1 += outb[(size_t)(NJ + k)*n + i];
            a2 += outb[(size_t)(2*NJ + k)*n + i];
        }
        int b = read_mask(bm, i, !badb);
        float safe_n = fmaxf(c0, 2.f);
        float var = (a2 - a1*a1/safe_n) / (safe_n - 1.f);
        if (b && c0 > 1.f) { sv = var; nv = 1.f; }
    }
    sv = wave_sum(sv); nv = wave_sum(nv);
    if (lane == 0) { atomicAdd(&bacc[9], sv); atomicAdd(&bacc[10], nv); }
    __syncthreads();

    // publish per-block row (device-scope), then accumulating ticket
    float* row = ws + 1024 + blockIdx.x*16;
    if (tid < 12) {
        float val = (tid == 8) ? __int_as_float(bmax) : bacc[tid];
        atomicExch((int*)&row[tid], __float_as_int(val));
    }
    if (tid == 0) {
        __threadfence();
        unsigned prev = atomicAdd((unsigned*)ws, 1u);
        if (prev % (unsigned)gridDim.x == (unsigned)gridDim.x - 1u) lastf = 1;
    }
    __syncthreads();
    if (!lastf) return;

    // last block: gather rows with atomic loads (distinct lines, parallel)
    if (tid < 12) bacc[tid] = 0.f;
    if (tid == 0) bmax = 0;
    __syncthreads();
    for (int t = tid; t < nbi*12; t += 256) {
        int r = t / 12, col = t % 12;
        int bits = atomicOr((int*)&ws[1024 + r*16 + col], 0);
        if (col == 8) atomicMax(&bmax, bits);
        else          atomicAdd(&bacc[col], __int_as_float(bits));
    }
    __syncthreads();
    if (tid != 0) return;

    float cxx=bacc[0], cxy=bacc[1], cxz=bacc[2];
    float cyy=bacc[3], cyz=bacc[4], czz=bacc[5];
    float sd=bacc[6], sd2=bacc[7], svv=bacc[9], niv=bacc[10];
    float maxd = __int_as_float(bmax);
    float pv = ctr[4], gv = ctr[5], nbm = ctr[6];

    // ellipsoid shape loss (closed-form symmetric 3x3 eigvals, double)
    float el = 0.0f;
    if (nh >= 10.0f) {
        double nn  = (double)nh;
        double axx = cxx/nn, axy = cxy/nn, axz = cxz/nn;
        double ayy = cyy/nn, ayz = cyz/nn, azz = czz/nn;
        double p1 = axy*axy + axz*axz + ayz*ayz;
        double q  = (axx + ayy + azz) / 3.0;
        double p2 = (axx-q)*(axx-q) + (ayy-q)*(ayy-q) + (azz-q)*(azz-q) + 2.0*p1;
        double e0, e2;
        if (p2 < 1e-300) { e0 = e2 = q; }
        else {
            double p = sqrt(p2 / 6.0);
            double bxx = (axx-q)/p, byy = (ayy-q)/p, bzz = (azz-q)/p;
            double bxy = axy/p, bxz = axz/p, byz = ayz/p;
            double detB = bxx*(byy*bzz - byz*byz) - bxy*(bxy*bzz - byz*bxz)
                        + bxz*(bxy*byz - byy*bxz);
            double r2 = fmin(1.0, fmax(-1.0, detB * 0.5));
            double phi = acos(r2) / 3.0;
            e2 = q + 2.0*p*cos(phi);                       // largest
            e0 = q + 2.0*p*cos(phi + 2.0943951023931953);  // smallest
        }
        double e1 = 3.0*q - e2 - e0;
        double ra = e1/(e2 + (double)EPSF) - 1.0;
        double rc = e0/(e2 + (double)EPSF) - 1.0;
        el = (float)(ra*ra + rc*rc);
    }
    // size consistency
    float diff = pv - gv;
    float vol = diff * diff;
    float rel = fabsf(diff) / (gv > 0.0f ? gv : 1.0f);
    float sc = (gv > 0.0f) ? vol + 0.5f*rel : vol;
    // surface smoothness
    float mean_var = svv / fmaxf(niv, 1.0f);
    float ss = ((nbm >= 5.0f) && (niv > 0.0f)) ? mean_var : 0.0f;
    // connectivity
    float conn = 0.0f;
    if (nh >= 5.0f) {
        float var = (sd2 - sd*sd/nh) / (nh - 1.0f);
        conn = var / (maxd + EPSF);
    }
    out[0] = el + sc + ss + conn;
}

extern "C" void kernel_launch(void* const* d_in, const int* in_sizes, int n_in,
                              void* d_out, int out_size, void* d_ws, size_t ws_size,
                              hipStream_t stream) {
    const float* points = (const float*)d_in[0];
    const float* segp   = (const float*)d_in[1];
    const void*  bmask  = d_in[2];
    const void*  hmask  = d_in[3];
    const void*  pmask  = d_in[4];
    const void*  gmask  = d_in[5];
    float* ws  = (float*)d_ws;
    float* out = (float*)d_out;
    int n = in_sizes[2];            // 8192
    int nbi = (n + 255) / 256;      // 32

    k_pairs<<<dim3(nbi, NJ), 256, 0, stream>>>(points, segp, bmask, hmask,
                                               pmask, gmask, ws, n, nbi);
    k_final<<<nbi, 256, 0, stream>>>(points, bmask, hmask, ws, out, n, nbi);
}